// Round 7
// baseline (15634.631 us; speedup 1.0000x reference)
//
#include <hip/hip_runtime.h>
#include <cstdint>
#include <cstddef>

// LSTM_Generator: 3-layer LSTM (H=100) + tanh projection. B=512, T=512, fp32.
//
// R6 = R5 structure + the correct occupancy attribute. Evidence across R0-R5:
//   __launch_bounds__(512,2)    -> VGPR 68-76, spills w[100] (min-only hint)
//   amdgpu_waves_per_eu(4,4)    -> ~120 VGPR, NO spill (R2 layer0, ~300us/layer)
// The allocator must be given a MAX waves/EU or it volunteers for 8 and spills.
// Structure: per layer, chunked [xw_gemm (Wih row in regs) -> lstm_rec (Whh row
// in regs, xw register-prefetched)] so xw chunk stays L3-resident and in-place
// hbuf is race-free by construction.
// ws layout: hbuf[512*512*100] | cbuf[512*100] | xw[512*CT*400].

#define HH 100   // hidden
#define G4 400   // 4*H
#define NB 512   // batch
#define NT 512   // timesteps

#define PIN44 __attribute__((amdgpu_flat_work_group_size(512, 512), \
                             amdgpu_waves_per_eu(4, 4)))
#define PIN22 __attribute__((amdgpu_flat_work_group_size(512, 512), \
                             amdgpu_waves_per_eu(2, 2)))

__device__ __forceinline__ float sigm(float x) {
  return 1.0f / (1.0f + __expf(-x));
}
__device__ __forceinline__ float tanh_(float x) {
  return 1.0f - 2.0f / (__expf(2.0f * x) + 1.0f);
}
// quad broadcasts: every lane of a quad gets lane (quad|k)'s value
__device__ __forceinline__ float qb1(float v) {
  return __int_as_float(__builtin_amdgcn_ds_swizzle(__float_as_int(v), 0x8055));
}
__device__ __forceinline__ float qb2(float v) {
  return __int_as_float(__builtin_amdgcn_ds_swizzle(__float_as_int(v), 0x80AA));
}
__device__ __forceinline__ float qb3(float v) {
  return __int_as_float(__builtin_amdgcn_ds_swizzle(__float_as_int(v), 0x80FF));
}

// ---------------- recurrent kernel ----------------
// MODE 0: xw precomputed in xsrc[NB][tlen][G4] (bias folded by gemm)
// MODE 1: K=1 input, xsrc = z[NB][NT], Wih=[G4,1], bias added here
template <int MODE>
__global__ PIN44 void lstm_rec(
    const float* __restrict__ xsrc,
    const float* __restrict__ Wih,
    const float* __restrict__ Whh,
    const float* __restrict__ bias,
    float* __restrict__ hseq,        // [NB, NT, HH]
    float* __restrict__ cbuf,        // [NB, HH]
    int t0, int tlen)
{
  const int b = blockIdx.x;
  const int tid = threadIdx.x;

  __shared__ __align__(16) float h_lds[2][HH];

  const bool isG = tid < G4;
  const int u = tid >> 2, g = tid & 3;     // quad map r=4u+g
  const int row = g * HH + u;

  float4 whh4[HH / 4];
  float bb = 0.f, c = 0.f, wih1 = 0.f;
  if (isG) {
    const float4* w4 = reinterpret_cast<const float4*>(Whh + (size_t)row * HH);
#pragma unroll
    for (int k = 0; k < HH / 4; ++k) whh4[k] = w4[k];
    if constexpr (MODE == 1) {
      wih1 = Wih[row];
      bb = bias[row];
    }
  }

  // init h, c for this chunk
  if (t0 == 0) {
    if (tid < HH) h_lds[0][tid] = 0.0f;
  } else {
    if (tid < HH) h_lds[0][tid] = hseq[((size_t)b * NT + (t0 - 1)) * HH + tid];
    if (isG && g == 0) c = cbuf[b * HH + u];
  }

  const float* xwb = xsrc + (size_t)b * tlen * G4;   // MODE 0
  const float* zb  = xsrc + (size_t)b * NT;          // MODE 1
  float* hb = hseq + (size_t)b * NT * HH;

  float xa_n = 0.f, zc = 0.f;
  if constexpr (MODE == 0) {
    if (isG) xa_n = xwb[tid];                        // prefetch s=0
  } else {
    zc = zb[t0];
  }
  __syncthreads();

  for (int s = 0; s < tlen; ++s) {
    const int cur = s & 1, nxt = cur ^ 1;

    float xa = 0.f, zn = 0.f;
    if constexpr (MODE == 0) {
      xa = xa_n;
      if (isG) {                                      // prefetch s+1 (clamped)
        int sn = (s + 1 < tlen) ? s + 1 : tlen - 1;
        xa_n = xwb[(size_t)sn * G4 + tid];
      }
    } else {
      int tn = (t0 + s + 1 < NT) ? t0 + s + 1 : NT - 1;
      zn = zb[tn];
    }

    if (isG) {
      float a0 = 0.f, a1 = 0.f, a2 = 0.f, a3 = 0.f;
      const float4* h4 = reinterpret_cast<const float4*>(h_lds[cur]);
#pragma unroll
      for (int k = 0; k < HH / 4; ++k) {
        float4 v = h4[k];                             // uniform -> broadcast
        a0 += v.x * whh4[k].x; a1 += v.y * whh4[k].y;
        a2 += v.z * whh4[k].z; a3 += v.w * whh4[k].w;
      }
      float acc = xa + ((a0 + a1) + (a2 + a3));
      if constexpr (MODE == 1) acc += bb + wih1 * zc;
      float act = (g == 2) ? tanh_(acc) : sigm(acc);
      float fv = qb1(act);
      float gv = qb2(act);
      float ov = qb3(act);
      if (g == 0) {                                   // lane 4u owns unit u
        c = fv * c + act * gv;
        float hv = ov * tanh_(c);
        h_lds[nxt][u] = hv;
        hb[(size_t)(t0 + s) * HH + u] = hv;
      }
    }
    if constexpr (MODE == 1) zc = zn;
    __syncthreads();
  }

  if (isG && g == 0) cbuf[b * HH + u] = c;            // carry to next chunk
}

// ---------------- input GEMM: xw = bias + x . WihT ----------------
__global__ PIN44 void xw_gemm(
    const float* __restrict__ hsrc,  // hbuf [NB, NT, HH]
    const float* __restrict__ Wih,   // [G4, HH]
    const float* __restrict__ bias,  // [G4]
    float* __restrict__ xw,          // [NB, tlen, G4]
    int t0, int tlen)
{
  const int b = blockIdx.x;
  const int tid = threadIdx.x;

  __shared__ __align__(16) float x_lds[32 * HH];     // 12.8 KB

  const bool isG = tid < G4;
  const int u = tid >> 2, g = tid & 3;
  const int row = g * HH + u;

  float4 wih4[HH / 4];
  float bb = 0.f;
  if (isG) {
    const float4* w4 = reinterpret_cast<const float4*>(Wih + (size_t)row * HH);
#pragma unroll
    for (int k = 0; k < HH / 4; ++k) wih4[k] = w4[k];
    bb = bias[row];
  }

  const float* hsb = hsrc + ((size_t)b * NT + t0) * HH;
  float* xwb = xw + (size_t)b * tlen * G4;

  for (int tt0 = 0; tt0 < tlen; tt0 += 32) {
    const int S = (tlen - tt0 < 32) ? (tlen - tt0) : 32;
    __syncthreads();                                 // protect x_lds reuse
    {
      const float4* src = reinterpret_cast<const float4*>(hsb + (size_t)tt0 * HH);
      float4* dst = reinterpret_cast<float4*>(x_lds);
      const int n4 = S * HH / 4;
      for (int i = tid; i < n4; i += 512) dst[i] = src[i];
    }
    __syncthreads();
    if (isG) {
      for (int tt = 0; tt < S; ++tt) {
        const float4* xr = reinterpret_cast<const float4*>(x_lds + tt * HH);
        float a0 = 0.f, a1 = 0.f, a2 = 0.f, a3 = 0.f;
#pragma unroll
        for (int k = 0; k < HH / 4; ++k) {
          float4 v = xr[k];                          // uniform -> broadcast
          a0 += v.x * wih4[k].x; a1 += v.y * wih4[k].y;
          a2 += v.z * wih4[k].z; a3 += v.w * wih4[k].w;
        }
        xwb[(size_t)(tt0 + tt) * G4 + tid] = bb + ((a0 + a1) + (a2 + a3));
      }
    }
  }
}

// ---------------- fallback: fused layer (R2 shape), only if ws too small ----
__global__ PIN22 void lstm_fused(
    const float* x,                   // [NB, NT, HH] (aliases hseq)
    const float* __restrict__ Wih,
    const float* __restrict__ Whh,
    const float* __restrict__ bias,
    float* hseq)
{
  const int b = blockIdx.x;
  const int tid = threadIdx.x;
  __shared__ __align__(16) float h_dbuf[2][HH];
  __shared__ __align__(16) float x_dbuf[2][HH];
  const bool isG = tid < G4;
  const int u = tid >> 2, g = tid & 3;
  const int row = g * HH + u;
  float whh[HH], wih[HH];
  float bb = 0.f, c = 0.f;
  if (isG) {
    const float4* wh4 = reinterpret_cast<const float4*>(Whh + (size_t)row * HH);
    const float4* wi4 = reinterpret_cast<const float4*>(Wih + (size_t)row * HH);
#pragma unroll
    for (int k = 0; k < HH / 4; ++k) {
      float4 a = wh4[k];
      whh[4 * k] = a.x; whh[4 * k + 1] = a.y; whh[4 * k + 2] = a.z; whh[4 * k + 3] = a.w;
      float4 bq = wi4[k];
      wih[4 * k] = bq.x; wih[4 * k + 1] = bq.y; wih[4 * k + 2] = bq.z; wih[4 * k + 3] = bq.w;
    }
    bb = bias[row];
  }
  if (tid < HH) h_dbuf[0][tid] = 0.0f;
  const float* xb = x + (size_t)b * NT * HH;
  float* hb = hseq + (size_t)b * NT * HH;
  const unsigned pf = (unsigned)(tid - 448);
  if (pf < 25u)
    reinterpret_cast<float4*>(x_dbuf[0])[pf] = reinterpret_cast<const float4*>(xb)[pf];
  __syncthreads();
  for (int t = 0; t < NT; ++t) {
    const int cur = t & 1, nxt = cur ^ 1;
    if (pf < 25u) {
      int tt = (t + 1 < NT) ? t + 1 : NT - 1;
      reinterpret_cast<float4*>(x_dbuf[nxt])[pf] =
          reinterpret_cast<const float4*>(xb + (size_t)tt * HH)[pf];
    }
    if (isG) {
      float a0 = 0.f, a1 = 0.f, a2 = 0.f, a3 = 0.f;
      const float4* x4 = reinterpret_cast<const float4*>(x_dbuf[cur]);
      const float4* h4 = reinterpret_cast<const float4*>(h_dbuf[cur]);
#pragma unroll
      for (int k = 0; k < HH / 4; ++k) {
        float4 v = x4[k];
        a0 += v.x * wih[4 * k];     a1 += v.y * wih[4 * k + 1];
        a2 += v.z * wih[4 * k + 2]; a3 += v.w * wih[4 * k + 3];
      }
#pragma unroll
      for (int k = 0; k < HH / 4; ++k) {
        float4 v = h4[k];
        a0 += v.x * whh[4 * k];     a1 += v.y * whh[4 * k + 1];
        a2 += v.z * whh[4 * k + 2]; a3 += v.w * whh[4 * k + 3];
      }
      float acc = bb + ((a0 + a1) + (a2 + a3));
      float act = (g == 2) ? tanh_(acc) : sigm(acc);
      float fv = qb1(act);
      float gv = qb2(act);
      float ov = qb3(act);
      if (g == 0) {
        c = fv * c + act * gv;
        float hv = ov * tanh_(c);
        h_dbuf[nxt][u] = hv;
        hb[(size_t)t * HH + u] = hv;
      }
    }
    __syncthreads();
  }
}

// ---------------- projection ----------------
__global__ __launch_bounds__(256) void proj_kernel(
    const float* __restrict__ hseq,
    const float* __restrict__ Wp,
    const float* __restrict__ bp,
    float* __restrict__ out)
{
  int idx = blockIdx.x * blockDim.x + threadIdx.x;
  if (idx >= NB * NT) return;
  const float4* h4 = reinterpret_cast<const float4*>(hseq + (size_t)idx * HH);
  const float4* w4 = reinterpret_cast<const float4*>(Wp);
  float a0 = 0.f, a1 = 0.f, a2 = 0.f, a3 = 0.f;
#pragma unroll
  for (int k = 0; k < HH / 4; ++k) {
    float4 h = h4[k];
    float4 w = w4[k];
    a0 += h.x * w.x; a1 += h.y * w.y; a2 += h.z * w.z; a3 += h.w * w.w;
  }
  out[idx] = tanh_(((a0 + a1) + (a2 + a3)) + bp[0]);
}

extern "C" void kernel_launch(void* const* d_in, const int* in_sizes, int n_in,
                              void* d_out, int out_size, void* d_ws, size_t ws_size,
                              hipStream_t stream) {
  const float* z    = (const float*)d_in[0];
  const float* Wih0 = (const float*)d_in[1];
  const float* Whh0 = (const float*)d_in[2];
  const float* b0   = (const float*)d_in[3];
  const float* Wih1 = (const float*)d_in[4];
  const float* Whh1 = (const float*)d_in[5];
  const float* b1   = (const float*)d_in[6];
  const float* Wih2 = (const float*)d_in[7];
  const float* Whh2 = (const float*)d_in[8];
  const float* b2   = (const float*)d_in[9];
  const float* Wp   = (const float*)d_in[10];
  const float* bp   = (const float*)d_in[11];
  float* out = (float*)d_out;

  float* hbuf = (float*)d_ws;                       // [NB,NT,HH]
  float* cbuf = hbuf + (size_t)NB * NT * HH;        // [NB,HH]
  float* xwb  = cbuf + (size_t)NB * HH;             // [NB,CT,G4]

  const size_t base_bytes = ((size_t)NB * NT * HH + (size_t)NB * HH) * 4;
  int CT = 0;
  for (int c : {128, 64, 32, 16, 8}) {
    if (base_bytes + (size_t)NB * c * G4 * 4 <= ws_size) { CT = c; break; }
  }

  // layer 0 (K=1): single full-length launch
  lstm_rec<1><<<NB, 512, 0, stream>>>(z, Wih0, Whh0, b0, hbuf, cbuf, 0, NT);

  const float* WihL[2] = {Wih1, Wih2};
  const float* WhhL[2] = {Whh1, Whh2};
  const float* bL[2]   = {b1, b2};

  if (CT > 0) {
    for (int l = 0; l < 2; ++l) {
      for (int t0 = 0; t0 < NT; t0 += CT) {
        xw_gemm<<<NB, 512, 0, stream>>>(hbuf, WihL[l], bL[l], xwb, t0, CT);
        lstm_rec<0><<<NB, 512, 0, stream>>>(xwb, WihL[l], WhhL[l], bL[l],
                                            hbuf, cbuf, t0, CT);
      }
    }
  } else {
    // ws too small for xw chunk: fused fallback (R2 shape, proven correct)
    lstm_fused<<<NB, 512, 0, stream>>>(hbuf, Wih1, Whh1, b1, hbuf);
    lstm_fused<<<NB, 512, 0, stream>>>(hbuf, Wih2, Whh2, b2, hbuf);
  }

  proj_kernel<<<(NB * NT + 255) / 256, 256, 0, stream>>>(hbuf, Wp, bp, out);
}

// Round 8
// 3332.999 us; speedup vs baseline: 4.6909x; 4.6909x over previous
//
#include <hip/hip_runtime.h>
#include <cstdint>
#include <cstddef>

// LSTM_Generator: 3-layer LSTM (H=100) + tanh projection. B=512, T=512, fp32.
//
// R7. Lessons R0-R6: (4,4)/launch_bounds pins -> compiler splits budget into
// 64 arch VGPR + AGPR + MEMORY scratch (R6 xw_gemm: 4.4GB fetch/dispatch).
// Only (2,2) never memory-spills (R2: VGPR=120, overflow to on-chip AGPR).
// So: (a) recurrent kernels (which MUST hold a 100-float Whh row) run at
// (2,2), 1 block/CU x 2 rounds; (b) the input GEMM has no recurrence, so it
// is a classic LDS-tiled GEMM (64x64 tile, [k][i] transposed staging,
// ~40 VGPR -- spill-proof by design), with Wih pre-permuted/transposed by a
// tiny wprep kernel and bias folded into the GEMM epilogue.
// ws: hbuf[NB*NT*HH] | cbuf[NB*HH] | wt1[HH*448] | wt2 | bp1[448] | bp2 | xw[NB*CT*G4]

#define HH 100   // hidden
#define G4 400   // 4*H
#define NB 512   // batch
#define NT 512   // timesteps
#define WSTR 448 // padded gate dim for wT/bperm
#define MT 64    // GEMM M tile
#define NTL 64   // GEMM N tile
#define NNT 7    // ceil(400/64)

#define PIN22 __attribute__((amdgpu_flat_work_group_size(512, 512), \
                             amdgpu_waves_per_eu(2, 2)))

__device__ __forceinline__ float sigm(float x) {
  return 1.0f / (1.0f + __expf(-x));
}
__device__ __forceinline__ float tanh_(float x) {
  return 1.0f - 2.0f / (__expf(2.0f * x) + 1.0f);
}
__device__ __forceinline__ float qb1(float v) {
  return __int_as_float(__builtin_amdgcn_ds_swizzle(__float_as_int(v), 0x8055));
}
__device__ __forceinline__ float qb2(float v) {
  return __int_as_float(__builtin_amdgcn_ds_swizzle(__float_as_int(v), 0x80AA));
}
__device__ __forceinline__ float qb3(float v) {
  return __int_as_float(__builtin_amdgcn_ds_swizzle(__float_as_int(v), 0x80FF));
}

// ---------------- weight prep: wT[k][n] = Wih[perm(n)][k], bias permuted ----
__global__ __launch_bounds__(256) void wprep(
    const float* __restrict__ Wih,   // [G4, HH]
    const float* __restrict__ bias,  // [G4]
    float* __restrict__ wT,          // [HH, WSTR]
    float* __restrict__ bp)          // [WSTR]
{
  int idx = blockIdx.x * blockDim.x + threadIdx.x;
  if (idx >= HH * WSTR) return;
  int k = idx / WSTR, n = idx % WSTR;
  float v = 0.0f;
  if (n < G4) {
    int row = (n & 3) * HH + (n >> 2);      // quad map: n=4u+g -> row g*H+u
    v = Wih[(size_t)row * HH + k];
  }
  wT[idx] = v;
  if (idx < WSTR) bp[idx] = (idx < G4) ? bias[(idx & 3) * HH + (idx >> 2)] : 0.0f;
}

// ---------------- input GEMM: xw[b][t][n] = bperm[n] + h[b][t0+t][:] . wT[:][n]
__global__ __launch_bounds__(256) void xw_gemm(
    const float* __restrict__ hsrc,  // [NB, NT, HH]
    const float* __restrict__ wT,    // [HH, WSTR]
    const float* __restrict__ bperm, // [WSTR]
    float* __restrict__ xw,          // [NB, CT, G4]
    int t0, int CT)
{
  const int mt = blockIdx.x / NNT, nt = blockIdx.x % NNT;
  const int m0 = mt * MT;
  const int b = m0 / CT, tr0 = m0 % CT;
  const int n0 = nt * NTL;
  const int tid = threadIdx.x;
  const int tx = tid & 15, ty = tid >> 4;

  __shared__ float Asub[HH][MT];     // 25.6 KB, [k][row]
  __shared__ float Bsub[HH][NTL];    // 25.6 KB, [k][col]

  // stage A transposed: item id -> (k4, i)
  for (int id = tid; id < MT * (HH / 4); id += 256) {
    const int k4 = id / MT, i = id % MT;
    const float4 v = *reinterpret_cast<const float4*>(
        hsrc + ((size_t)b * NT + (t0 + tr0 + i)) * HH + 4 * k4);
    Asub[4 * k4 + 0][i] = v.x;
    Asub[4 * k4 + 1][i] = v.y;
    Asub[4 * k4 + 2][i] = v.z;
    Asub[4 * k4 + 3][i] = v.w;
  }
  // stage B: contiguous rows of wT
  for (int id = tid; id < HH * (NTL / 4); id += 256) {
    const int k = id / (NTL / 4), q = id % (NTL / 4);
    const float4 v = *reinterpret_cast<const float4*>(wT + (size_t)k * WSTR + n0 + 4 * q);
    *reinterpret_cast<float4*>(&Bsub[k][4 * q]) = v;
  }
  __syncthreads();

  float acc[4][4] = {};
#pragma unroll 4
  for (int k = 0; k < HH; ++k) {
    const float4 a = *reinterpret_cast<const float4*>(&Asub[k][4 * ty]);
    const float4 bq = *reinterpret_cast<const float4*>(&Bsub[k][4 * tx]);
    acc[0][0] += a.x * bq.x; acc[0][1] += a.x * bq.y; acc[0][2] += a.x * bq.z; acc[0][3] += a.x * bq.w;
    acc[1][0] += a.y * bq.x; acc[1][1] += a.y * bq.y; acc[1][2] += a.y * bq.z; acc[1][3] += a.y * bq.w;
    acc[2][0] += a.z * bq.x; acc[2][1] += a.z * bq.y; acc[2][2] += a.z * bq.z; acc[2][3] += a.z * bq.w;
    acc[3][0] += a.w * bq.x; acc[3][1] += a.w * bq.y; acc[3][2] += a.w * bq.z; acc[3][3] += a.w * bq.w;
  }

  const int n = n0 + 4 * tx;
  if (n + 3 < G4) {
    const float4 bpq = *reinterpret_cast<const float4*>(bperm + n);
#pragma unroll
    for (int jr = 0; jr < 4; ++jr) {
      float4 o;
      o.x = acc[jr][0] + bpq.x; o.y = acc[jr][1] + bpq.y;
      o.z = acc[jr][2] + bpq.z; o.w = acc[jr][3] + bpq.w;
      *reinterpret_cast<float4*>(
          &xw[((size_t)b * CT + tr0 + 4 * ty + jr) * G4 + n]) = o;
    }
  }
}

// ---------------- recurrent kernel ----------------
// MODE 0: xw precomputed (bias folded), xsrc=[NB][tlen][G4]
// MODE 1: K=1 input, xsrc=z[NB][NT], Wih=[G4,1], bias added here
template <int MODE>
__global__ PIN22 void lstm_rec(
    const float* __restrict__ xsrc,
    const float* __restrict__ Wih,
    const float* __restrict__ Whh,
    const float* __restrict__ bias,
    float* __restrict__ hseq,        // [NB, NT, HH]
    float* __restrict__ cbuf,        // [NB, HH]
    int t0, int tlen)
{
  const int b = blockIdx.x;
  const int tid = threadIdx.x;

  __shared__ __align__(16) float h_lds[2][HH];

  const bool isG = tid < G4;
  const int u = tid >> 2, g = tid & 3;     // quad map r=4u+g
  const int row = g * HH + u;

  float4 whh4[HH / 4];
  float bb = 0.f, c = 0.f, wih1 = 0.f;
  if (isG) {
    const float4* w4 = reinterpret_cast<const float4*>(Whh + (size_t)row * HH);
#pragma unroll
    for (int k = 0; k < HH / 4; ++k) whh4[k] = w4[k];
    if constexpr (MODE == 1) {
      wih1 = Wih[row];
      bb = bias[row];
    }
  }

  if (t0 == 0) {
    if (tid < HH) h_lds[0][tid] = 0.0f;
  } else {
    if (tid < HH) h_lds[0][tid] = hseq[((size_t)b * NT + (t0 - 1)) * HH + tid];
    if (isG && g == 0) c = cbuf[b * HH + u];
  }

  const float* xwb = xsrc + (size_t)b * tlen * G4;   // MODE 0
  const float* zb  = xsrc + (size_t)b * NT;          // MODE 1
  float* hb = hseq + (size_t)b * NT * HH;

  float xa_n = 0.f, zc = 0.f;
  if constexpr (MODE == 0) {
    if (isG) xa_n = xwb[tid];                        // prefetch s=0
  } else {
    zc = zb[t0];
  }
  __syncthreads();

  for (int s = 0; s < tlen; ++s) {
    const int cur = s & 1, nxt = cur ^ 1;

    float xa = 0.f, zn = 0.f;
    if constexpr (MODE == 0) {
      xa = xa_n;
      if (isG) {
        int sn = (s + 1 < tlen) ? s + 1 : tlen - 1;
        xa_n = xwb[(size_t)sn * G4 + tid];           // prefetch next step
      }
    } else {
      int tn = (t0 + s + 1 < NT) ? t0 + s + 1 : NT - 1;
      zn = zb[tn];
    }

    if (isG) {
      float a0 = 0.f, a1 = 0.f, a2 = 0.f, a3 = 0.f;
      const float4* h4 = reinterpret_cast<const float4*>(h_lds[cur]);
#pragma unroll
      for (int k = 0; k < HH / 4; ++k) {
        float4 v = h4[k];                            // uniform -> broadcast
        a0 += v.x * whh4[k].x; a1 += v.y * whh4[k].y;
        a2 += v.z * whh4[k].z; a3 += v.w * whh4[k].w;
      }
      float acc = xa + ((a0 + a1) + (a2 + a3));
      if constexpr (MODE == 1) acc += bb + wih1 * zc;
      float act = (g == 2) ? tanh_(acc) : sigm(acc);
      float fv = qb1(act);
      float gv = qb2(act);
      float ov = qb3(act);
      if (g == 0) {                                  // lane 4u owns unit u
        c = fv * c + act * gv;
        float hv = ov * tanh_(c);
        h_lds[nxt][u] = hv;
        hb[(size_t)(t0 + s) * HH + u] = hv;
      }
    }
    if constexpr (MODE == 1) zc = zn;
    __syncthreads();
  }

  if (isG && g == 0) cbuf[b * HH + u] = c;
}

// ---------------- fallback fused layer (only if ws too small) ----------------
__global__ PIN22 void lstm_fused(
    const float* x,
    const float* __restrict__ Wih,
    const float* __restrict__ Whh,
    const float* __restrict__ bias,
    float* hseq)
{
  const int b = blockIdx.x;
  const int tid = threadIdx.x;
  __shared__ __align__(16) float h_dbuf[2][HH];
  __shared__ __align__(16) float x_dbuf[2][HH];
  const bool isG = tid < G4;
  const int u = tid >> 2, g = tid & 3;
  const int row = g * HH + u;
  float whh[HH], wih[HH];
  float bb = 0.f, c = 0.f;
  if (isG) {
    const float4* wh4 = reinterpret_cast<const float4*>(Whh + (size_t)row * HH);
    const float4* wi4 = reinterpret_cast<const float4*>(Wih + (size_t)row * HH);
#pragma unroll
    for (int k = 0; k < HH / 4; ++k) {
      float4 a = wh4[k];
      whh[4 * k] = a.x; whh[4 * k + 1] = a.y; whh[4 * k + 2] = a.z; whh[4 * k + 3] = a.w;
      float4 bq = wi4[k];
      wih[4 * k] = bq.x; wih[4 * k + 1] = bq.y; wih[4 * k + 2] = bq.z; wih[4 * k + 3] = bq.w;
    }
    bb = bias[row];
  }
  if (tid < HH) h_dbuf[0][tid] = 0.0f;
  const float* xb = x + (size_t)b * NT * HH;
  float* hb = hseq + (size_t)b * NT * HH;
  const unsigned pf = (unsigned)(tid - 448);
  if (pf < 25u)
    reinterpret_cast<float4*>(x_dbuf[0])[pf] = reinterpret_cast<const float4*>(xb)[pf];
  __syncthreads();
  for (int t = 0; t < NT; ++t) {
    const int cur = t & 1, nxt = cur ^ 1;
    if (pf < 25u) {
      int tt = (t + 1 < NT) ? t + 1 : NT - 1;
      reinterpret_cast<float4*>(x_dbuf[nxt])[pf] =
          reinterpret_cast<const float4*>(xb + (size_t)tt * HH)[pf];
    }
    if (isG) {
      float a0 = 0.f, a1 = 0.f, a2 = 0.f, a3 = 0.f;
      const float4* x4 = reinterpret_cast<const float4*>(x_dbuf[cur]);
      const float4* h4 = reinterpret_cast<const float4*>(h_dbuf[cur]);
#pragma unroll
      for (int k = 0; k < HH / 4; ++k) {
        float4 v = x4[k];
        a0 += v.x * wih[4 * k];     a1 += v.y * wih[4 * k + 1];
        a2 += v.z * wih[4 * k + 2]; a3 += v.w * wih[4 * k + 3];
      }
#pragma unroll
      for (int k = 0; k < HH / 4; ++k) {
        float4 v = h4[k];
        a0 += v.x * whh[4 * k];     a1 += v.y * whh[4 * k + 1];
        a2 += v.z * whh[4 * k + 2]; a3 += v.w * whh[4 * k + 3];
      }
      float acc = bb + ((a0 + a1) + (a2 + a3));
      float act = (g == 2) ? tanh_(acc) : sigm(acc);
      float fv = qb1(act);
      float gv = qb2(act);
      float ov = qb3(act);
      if (g == 0) {
        c = fv * c + act * gv;
        float hv = ov * tanh_(c);
        h_dbuf[nxt][u] = hv;
        hb[(size_t)t * HH + u] = hv;
      }
    }
    __syncthreads();
  }
}

// ---------------- projection ----------------
__global__ __launch_bounds__(256) void proj_kernel(
    const float* __restrict__ hseq,
    const float* __restrict__ Wp,
    const float* __restrict__ bp,
    float* __restrict__ out)
{
  int idx = blockIdx.x * blockDim.x + threadIdx.x;
  if (idx >= NB * NT) return;
  const float4* h4 = reinterpret_cast<const float4*>(hseq + (size_t)idx * HH);
  const float4* w4 = reinterpret_cast<const float4*>(Wp);
  float a0 = 0.f, a1 = 0.f, a2 = 0.f, a3 = 0.f;
#pragma unroll
  for (int k = 0; k < HH / 4; ++k) {
    float4 h = h4[k];
    float4 w = w4[k];
    a0 += h.x * w.x; a1 += h.y * w.y; a2 += h.z * w.z; a3 += h.w * w.w;
  }
  out[idx] = tanh_(((a0 + a1) + (a2 + a3)) + bp[0]);
}

extern "C" void kernel_launch(void* const* d_in, const int* in_sizes, int n_in,
                              void* d_out, int out_size, void* d_ws, size_t ws_size,
                              hipStream_t stream) {
  const float* z    = (const float*)d_in[0];
  const float* Wih0 = (const float*)d_in[1];
  const float* Whh0 = (const float*)d_in[2];
  const float* b0   = (const float*)d_in[3];
  const float* Wih1 = (const float*)d_in[4];
  const float* Whh1 = (const float*)d_in[5];
  const float* b1   = (const float*)d_in[6];
  const float* Wih2 = (const float*)d_in[7];
  const float* Whh2 = (const float*)d_in[8];
  const float* b2   = (const float*)d_in[9];
  const float* Wp   = (const float*)d_in[10];
  const float* bp   = (const float*)d_in[11];
  float* out = (float*)d_out;

  float* hbuf = (float*)d_ws;                       // [NB,NT,HH]
  float* cbuf = hbuf + (size_t)NB * NT * HH;        // [NB,HH]
  float* wt1  = cbuf + (size_t)NB * HH;             // [HH,WSTR]
  float* wt2  = wt1 + (size_t)HH * WSTR;
  float* bp1  = wt2 + (size_t)HH * WSTR;            // [WSTR]
  float* bp2  = bp1 + WSTR;
  float* xwb  = bp2 + WSTR;                         // [NB,CT,G4]

  const size_t fixed = (size_t)(bp2 + WSTR - hbuf) * 4;
  int CT = 0;
  for (int c : {128, 64}) {
    if (fixed + (size_t)NB * c * G4 * 4 <= ws_size) { CT = c; break; }
  }

  // layer 0 (K=1): full-length
  lstm_rec<1><<<NB, 512, 0, stream>>>(z, Wih0, Whh0, b0, hbuf, cbuf, 0, NT);

  if (CT > 0) {
    wprep<<<(HH * WSTR + 255) / 256, 256, 0, stream>>>(Wih1, b1, wt1, bp1);
    wprep<<<(HH * WSTR + 255) / 256, 256, 0, stream>>>(Wih2, b2, wt2, bp2);
    const float* wtL[2] = {wt1, wt2};
    const float* bpL[2] = {bp1, bp2};
    const float* WhhL[2] = {Whh1, Whh2};
    const int gemm_grid = (NB * CT / MT) * NNT;
    for (int l = 0; l < 2; ++l) {
      for (int t0 = 0; t0 < NT; t0 += CT) {
        xw_gemm<<<gemm_grid, 256, 0, stream>>>(hbuf, wtL[l], bpL[l], xwb, t0, CT);
        lstm_rec<0><<<NB, 512, 0, stream>>>(xwb, nullptr, WhhL[l], nullptr,
                                            hbuf, cbuf, t0, CT);
      }
    }
  } else {
    lstm_fused<<<NB, 512, 0, stream>>>(hbuf, Wih1, Whh1, b1, hbuf);
    lstm_fused<<<NB, 512, 0, stream>>>(hbuf, Wih2, Whh2, b2, hbuf);
  }

  proj_kernel<<<(NB * NT + 255) / 256, 256, 0, stream>>>(hbuf, Wp, bp, out);
}

// Round 9
// 2700.756 us; speedup vs baseline: 5.7890x; 1.2341x over previous
//
#include <hip/hip_runtime.h>
#include <cstdint>
#include <cstddef>

// LSTM_Generator: 3-layer LSTM (H=100) + tanh projection. B=512, T=512, fp32.
//
// R8. Register-allocator findings (R0-R7): the ONLY no-spill recurrent kernel
// was R2-layer0: (4,4) + 512thr + scalar float w[100] + minimal body. R6/R7's
// lstm_rec (float4 w, per-iter index mul, clamped prefetch) exceeded the
// 128-reg budget by a handful of values -> cascade spill (VGPR 68-88, SGPR
// 112, ~3x step cost). R8 re-clones the proven shape exactly:
//   - scalar float w[100]
//   - pointer-bump addressing (no per-iter 64-bit mul)
//   - register-rotated 1-step-ahead xa/z prefetch
//   - chunk init (h from hseq, c from cbuf) and epilogue outside the loop
// Structure unchanged from R7: per layer, chunked [tiled xw_gemm -> lstm_rec],
// CT=128, quad-permuted wT/bias so rec reads xw[s][tid] directly.
// ws: hbuf[NB*NT*HH] | cbuf[NB*HH] | wt1[HH*448] | wt2 | bp1[448] | bp2 | xw[NB*CT*G4]

#define HH 100   // hidden
#define G4 400   // 4*H
#define NB 512   // batch
#define NT 512   // timesteps
#define WSTR 448 // padded gate dim for wT/bperm
#define MT 64    // GEMM M tile
#define NTL 64   // GEMM N tile
#define NNT 7    // ceil(400/64)

#define PIN44 __attribute__((amdgpu_flat_work_group_size(512, 512), \
                             amdgpu_waves_per_eu(4, 4)))
#define PIN22 __attribute__((amdgpu_flat_work_group_size(512, 512), \
                             amdgpu_waves_per_eu(2, 2)))

__device__ __forceinline__ float sigm(float x) {
  return 1.0f / (1.0f + __expf(-x));
}
__device__ __forceinline__ float tanh_(float x) {
  return 1.0f - 2.0f / (__expf(2.0f * x) + 1.0f);
}
__device__ __forceinline__ float qb1(float v) {
  return __int_as_float(__builtin_amdgcn_ds_swizzle(__float_as_int(v), 0x8055));
}
__device__ __forceinline__ float qb2(float v) {
  return __int_as_float(__builtin_amdgcn_ds_swizzle(__float_as_int(v), 0x80AA));
}
__device__ __forceinline__ float qb3(float v) {
  return __int_as_float(__builtin_amdgcn_ds_swizzle(__float_as_int(v), 0x80FF));
}

// ---------------- weight prep: wT[k][n] = Wih[perm(n)][k], bias permuted ----
__global__ __launch_bounds__(256) void wprep(
    const float* __restrict__ Wih,   // [G4, HH]
    const float* __restrict__ bias,  // [G4]
    float* __restrict__ wT,          // [HH, WSTR]
    float* __restrict__ bp)          // [WSTR]
{
  int idx = blockIdx.x * blockDim.x + threadIdx.x;
  if (idx >= HH * WSTR) return;
  int k = idx / WSTR, n = idx % WSTR;
  float v = 0.0f;
  if (n < G4) {
    int row = (n & 3) * HH + (n >> 2);      // quad map: n=4u+g -> row g*H+u
    v = Wih[(size_t)row * HH + k];
  }
  wT[idx] = v;
  if (idx < WSTR) bp[idx] = (idx < G4) ? bias[(idx & 3) * HH + (idx >> 2)] : 0.0f;
}

// ---------------- input GEMM: xw[b][t][n] = bperm[n] + h[b][t0+t][:] . wT[:][n]
__global__ __launch_bounds__(256) void xw_gemm(
    const float* __restrict__ hsrc,  // [NB, NT, HH]
    const float* __restrict__ wT,    // [HH, WSTR]
    const float* __restrict__ bperm, // [WSTR]
    float* __restrict__ xw,          // [NB, CT, G4]
    int t0, int CT)
{
  const int mt = blockIdx.x / NNT, nt = blockIdx.x % NNT;
  const int m0 = mt * MT;
  const int b = m0 / CT, tr0 = m0 % CT;
  const int n0 = nt * NTL;
  const int tid = threadIdx.x;
  const int tx = tid & 15, ty = tid >> 4;

  __shared__ float Asub[HH][MT];     // 25.6 KB, [k][row]
  __shared__ float Bsub[HH][NTL];    // 25.6 KB, [k][col]

  for (int id = tid; id < MT * (HH / 4); id += 256) {
    const int k4 = id / MT, i = id % MT;
    const float4 v = *reinterpret_cast<const float4*>(
        hsrc + ((size_t)b * NT + (t0 + tr0 + i)) * HH + 4 * k4);
    Asub[4 * k4 + 0][i] = v.x;
    Asub[4 * k4 + 1][i] = v.y;
    Asub[4 * k4 + 2][i] = v.z;
    Asub[4 * k4 + 3][i] = v.w;
  }
  for (int id = tid; id < HH * (NTL / 4); id += 256) {
    const int k = id / (NTL / 4), q = id % (NTL / 4);
    const float4 v = *reinterpret_cast<const float4*>(wT + (size_t)k * WSTR + n0 + 4 * q);
    *reinterpret_cast<float4*>(&Bsub[k][4 * q]) = v;
  }
  __syncthreads();

  float acc[4][4] = {};
#pragma unroll 4
  for (int k = 0; k < HH; ++k) {
    const float4 a = *reinterpret_cast<const float4*>(&Asub[k][4 * ty]);
    const float4 bq = *reinterpret_cast<const float4*>(&Bsub[k][4 * tx]);
    acc[0][0] += a.x * bq.x; acc[0][1] += a.x * bq.y; acc[0][2] += a.x * bq.z; acc[0][3] += a.x * bq.w;
    acc[1][0] += a.y * bq.x; acc[1][1] += a.y * bq.y; acc[1][2] += a.y * bq.z; acc[1][3] += a.y * bq.w;
    acc[2][0] += a.z * bq.x; acc[2][1] += a.z * bq.y; acc[2][2] += a.z * bq.z; acc[2][3] += a.z * bq.w;
    acc[3][0] += a.w * bq.x; acc[3][1] += a.w * bq.y; acc[3][2] += a.w * bq.z; acc[3][3] += a.w * bq.w;
  }

  const int n = n0 + 4 * tx;
  if (n + 3 < G4) {
    const float4 bpq = *reinterpret_cast<const float4*>(bperm + n);
#pragma unroll
    for (int jr = 0; jr < 4; ++jr) {
      float4 o;
      o.x = acc[jr][0] + bpq.x; o.y = acc[jr][1] + bpq.y;
      o.z = acc[jr][2] + bpq.z; o.w = acc[jr][3] + bpq.w;
      *reinterpret_cast<float4*>(
          &xw[((size_t)b * CT + tr0 + 4 * ty + jr) * G4 + n]) = o;
    }
  }
}

// ---------------- recurrent kernel (R2-layer0 proven shape) ----------------
// MODE 0: xw precomputed (bias folded, quad-permuted), xsrc=[NB][tlen][G4]
// MODE 1: K=1 input, xsrc=z[NB][NT], Wih=[G4,1], bias added here
template <int MODE>
__global__ PIN44 void lstm_rec(
    const float* __restrict__ xsrc,
    const float* __restrict__ Wih,
    const float* __restrict__ Whh,
    const float* __restrict__ bias,
    float* __restrict__ hseq,        // [NB, NT, HH]
    float* __restrict__ cbuf,        // [NB, HH]
    int t0, int tlen)
{
  const int b = blockIdx.x;
  const int tid = threadIdx.x;

  __shared__ __align__(16) float h_lds[2][HH];

  const bool isG = tid < G4;
  const int u = tid >> 2, g = tid & 3;     // quad map r=4u+g
  const int row = g * HH + u;

  float w[HH];                             // scalar array: proven no-spill
  float bb = 0.f, c = 0.f, wih1 = 0.f;
  if (isG) {
    const float4* w4 = reinterpret_cast<const float4*>(Whh + (size_t)row * HH);
#pragma unroll
    for (int k = 0; k < HH / 4; ++k) {
      float4 v = w4[k];
      w[4 * k] = v.x; w[4 * k + 1] = v.y; w[4 * k + 2] = v.z; w[4 * k + 3] = v.w;
    }
    if constexpr (MODE == 1) {
      wih1 = Wih[row];
      bb = bias[row];
    }
  }

  // chunk init (outside steady-state loop)
  if (t0 == 0) {
    if (tid < HH) h_lds[0][tid] = 0.0f;
  } else {
    if (tid < HH) h_lds[0][tid] = hseq[((size_t)b * NT + (t0 - 1)) * HH + tid];
    if (isG && g == 0) c = cbuf[b * HH + u];
  }

  // pointer-bump addressing, no per-iter index arithmetic
  const float* xwp = xsrc + (size_t)b * tlen * G4 + tid;   // MODE 0
  const float* zp  = xsrc + (size_t)b * NT + t0;           // MODE 1
  float* hp = hseq + ((size_t)b * NT + t0) * HH;

  float xa_n = 0.f, zc = 0.f;
  if constexpr (MODE == 0) {
    if (isG) xa_n = *xwp;                  // prefetch step 0
  } else {
    zc = *zp;
  }
  __syncthreads();

  for (int s = 0; s < tlen; ++s) {
    const int cur = s & 1, nxt = cur ^ 1;

    float xa = 0.f, zn = 0.f;
    if constexpr (MODE == 0) {
      xa = xa_n;
      xwp += (s + 1 < tlen) ? G4 : 0;      // scalar-select bump
      if (isG) xa_n = *xwp;                // prefetch next step
    } else {
      zp += (s + 1 < tlen) ? 1 : 0;
      zn = *zp;
    }

    if (isG) {
      float a0 = 0.f, a1 = 0.f, a2 = 0.f, a3 = 0.f;
      const float4* h4 = reinterpret_cast<const float4*>(h_lds[cur]);
#pragma unroll
      for (int k = 0; k < HH / 4; ++k) {
        float4 v = h4[k];                  // uniform address -> broadcast
        a0 += v.x * w[4 * k];     a1 += v.y * w[4 * k + 1];
        a2 += v.z * w[4 * k + 2]; a3 += v.w * w[4 * k + 3];
      }
      float acc = xa + ((a0 + a1) + (a2 + a3));
      if constexpr (MODE == 1) acc += bb + wih1 * zc;
      float act = (g == 2) ? tanh_(acc) : sigm(acc);
      float fv = qb1(act);
      float gv = qb2(act);
      float ov = qb3(act);
      if (g == 0) {                        // lane 4u owns unit u's c,h
        c = fv * c + act * gv;
        float hv = ov * tanh_(c);
        h_lds[nxt][u] = hv;
        hp[u] = hv;
      }
    }
    hp += HH;
    if constexpr (MODE == 1) zc = zn;
    __syncthreads();
  }

  if (isG && g == 0) cbuf[b * HH + u] = c;
}

// ---------------- fallback fused layer (only if ws too small) ----------------
__global__ PIN22 void lstm_fused(
    const float* x,
    const float* __restrict__ Wih,
    const float* __restrict__ Whh,
    const float* __restrict__ bias,
    float* hseq)
{
  const int b = blockIdx.x;
  const int tid = threadIdx.x;
  __shared__ __align__(16) float h_dbuf[2][HH];
  __shared__ __align__(16) float x_dbuf[2][HH];
  const bool isG = tid < G4;
  const int u = tid >> 2, g = tid & 3;
  const int row = g * HH + u;
  float whh[HH], wih[HH];
  float bb = 0.f, c = 0.f;
  if (isG) {
    const float4* wh4 = reinterpret_cast<const float4*>(Whh + (size_t)row * HH);
    const float4* wi4 = reinterpret_cast<const float4*>(Wih + (size_t)row * HH);
#pragma unroll
    for (int k = 0; k < HH / 4; ++k) {
      float4 a = wh4[k];
      whh[4 * k] = a.x; whh[4 * k + 1] = a.y; whh[4 * k + 2] = a.z; whh[4 * k + 3] = a.w;
      float4 bq = wi4[k];
      wih[4 * k] = bq.x; wih[4 * k + 1] = bq.y; wih[4 * k + 2] = bq.z; wih[4 * k + 3] = bq.w;
    }
    bb = bias[row];
  }
  if (tid < HH) h_dbuf[0][tid] = 0.0f;
  const float* xb = x + (size_t)b * NT * HH;
  float* hb = hseq + (size_t)b * NT * HH;
  const unsigned pf = (unsigned)(tid - 448);
  if (pf < 25u)
    reinterpret_cast<float4*>(x_dbuf[0])[pf] = reinterpret_cast<const float4*>(xb)[pf];
  __syncthreads();
  for (int t = 0; t < NT; ++t) {
    const int cur = t & 1, nxt = cur ^ 1;
    if (pf < 25u) {
      int tt = (t + 1 < NT) ? t + 1 : NT - 1;
      reinterpret_cast<float4*>(x_dbuf[nxt])[pf] =
          reinterpret_cast<const float4*>(xb + (size_t)tt * HH)[pf];
    }
    if (isG) {
      float a0 = 0.f, a1 = 0.f, a2 = 0.f, a3 = 0.f;
      const float4* x4 = reinterpret_cast<const float4*>(x_dbuf[cur]);
      const float4* h4 = reinterpret_cast<const float4*>(h_dbuf[cur]);
#pragma unroll
      for (int k = 0; k < HH / 4; ++k) {
        float4 v = x4[k];
        a0 += v.x * wih[4 * k];     a1 += v.y * wih[4 * k + 1];
        a2 += v.z * wih[4 * k + 2]; a3 += v.w * wih[4 * k + 3];
      }
#pragma unroll
      for (int k = 0; k < HH / 4; ++k) {
        float4 v = h4[k];
        a0 += v.x * whh[4 * k];     a1 += v.y * whh[4 * k + 1];
        a2 += v.z * whh[4 * k + 2]; a3 += v.w * whh[4 * k + 3];
      }
      float acc = bb + ((a0 + a1) + (a2 + a3));
      float act = (g == 2) ? tanh_(acc) : sigm(acc);
      float fv = qb1(act);
      float gv = qb2(act);
      float ov = qb3(act);
      if (g == 0) {
        c = fv * c + act * gv;
        float hv = ov * tanh_(c);
        h_dbuf[nxt][u] = hv;
        hb[(size_t)t * HH + u] = hv;
      }
    }
    __syncthreads();
  }
}

// ---------------- projection ----------------
__global__ __launch_bounds__(256) void proj_kernel(
    const float* __restrict__ hseq,
    const float* __restrict__ Wp,
    const float* __restrict__ bp,
    float* __restrict__ out)
{
  int idx = blockIdx.x * blockDim.x + threadIdx.x;
  if (idx >= NB * NT) return;
  const float4* h4 = reinterpret_cast<const float4*>(hseq + (size_t)idx * HH);
  const float4* w4 = reinterpret_cast<const float4*>(Wp);
  float a0 = 0.f, a1 = 0.f, a2 = 0.f, a3 = 0.f;
#pragma unroll
  for (int k = 0; k < HH / 4; ++k) {
    float4 h = h4[k];
    float4 w = w4[k];
    a0 += h.x * w.x; a1 += h.y * w.y; a2 += h.z * w.z; a3 += h.w * w.w;
  }
  out[idx] = tanh_(((a0 + a1) + (a2 + a3)) + bp[0]);
}

extern "C" void kernel_launch(void* const* d_in, const int* in_sizes, int n_in,
                              void* d_out, int out_size, void* d_ws, size_t ws_size,
                              hipStream_t stream) {
  const float* z    = (const float*)d_in[0];
  const float* Wih0 = (const float*)d_in[1];
  const float* Whh0 = (const float*)d_in[2];
  const float* b0   = (const float*)d_in[3];
  const float* Wih1 = (const float*)d_in[4];
  const float* Whh1 = (const float*)d_in[5];
  const float* b1   = (const float*)d_in[6];
  const float* Wih2 = (const float*)d_in[7];
  const float* Whh2 = (const float*)d_in[8];
  const float* b2   = (const float*)d_in[9];
  const float* Wp   = (const float*)d_in[10];
  const float* bp   = (const float*)d_in[11];
  float* out = (float*)d_out;

  float* hbuf = (float*)d_ws;                       // [NB,NT,HH]
  float* cbuf = hbuf + (size_t)NB * NT * HH;        // [NB,HH]
  float* wt1  = cbuf + (size_t)NB * HH;             // [HH,WSTR]
  float* wt2  = wt1 + (size_t)HH * WSTR;
  float* bp1  = wt2 + (size_t)HH * WSTR;            // [WSTR]
  float* bp2  = bp1 + WSTR;
  float* xwb  = bp2 + WSTR;                         // [NB,CT,G4]

  const size_t fixed = (size_t)(bp2 + WSTR - hbuf) * 4;
  int CT = 0;
  for (int c : {128, 64}) {
    if (fixed + (size_t)NB * c * G4 * 4 <= ws_size) { CT = c; break; }
  }

  // layer 0 (K=1): full-length
  lstm_rec<1><<<NB, 512, 0, stream>>>(z, Wih0, Whh0, b0, hbuf, cbuf, 0, NT);

  if (CT > 0) {
    wprep<<<(HH * WSTR + 255) / 256, 256, 0, stream>>>(Wih1, b1, wt1, bp1);
    wprep<<<(HH * WSTR + 255) / 256, 256, 0, stream>>>(Wih2, b2, wt2, bp2);
    const float* wtL[2] = {wt1, wt2};
    const float* bpL[2] = {bp1, bp2};
    const float* WhhL[2] = {Whh1, Whh2};
    const int gemm_grid = (NB * CT / MT) * NNT;
    for (int l = 0; l < 2; ++l) {
      for (int t0 = 0; t0 < NT; t0 += CT) {
        xw_gemm<<<gemm_grid, 256, 0, stream>>>(hbuf, wtL[l], bpL[l], xwb, t0, CT);
        lstm_rec<0><<<NB, 512, 0, stream>>>(xwb, nullptr, WhhL[l], nullptr,
                                            hbuf, cbuf, t0, CT);
      }
    }
  } else {
    lstm_fused<<<NB, 512, 0, stream>>>(hbuf, Wih1, Whh1, b1, hbuf);
    lstm_fused<<<NB, 512, 0, stream>>>(hbuf, Wih2, Whh2, b2, hbuf);
  }

  proj_kernel<<<(NB * NT + 255) / 256, 256, 0, stream>>>(hbuf, Wp, bp, out);
}